// Round 2
// baseline (6695.865 us; speedup 1.0000x reference)
//
#include <hip/hip_runtime.h>
#include <math.h>

#define BB 8
#define NN 4096
#define CC 256
#define DD 64
#define MM 1024
#define KNB 16
#define OC 259

// ---------------------------------------------------------------------------
// Transpose feature_map (B,C,N) -> (B,N,C) for coalesced per-point gathers.
__global__ __launch_bounds__(256) void transpose_fm(const float* __restrict__ fm,
                                                    float* __restrict__ fm_t) {
  __shared__ float tile[64][65];
  int b = blockIdx.z;
  int n0 = blockIdx.x * 64;
  int c0 = blockIdx.y * 64;
  const float* src = fm + (size_t)b * CC * NN;
  float* dst = fm_t + (size_t)b * NN * CC;
  int tx = threadIdx.x, ty = threadIdx.y;
  for (int r = ty; r < 64; r += 4)
    tile[r][tx] = src[(size_t)(c0 + r) * NN + n0 + tx];
  __syncthreads();
  for (int r = ty; r < 64; r += 4)
    dst[(size_t)(n0 + r) * CC + c0 + tx] = tile[tx][r];
}

// ---------------------------------------------------------------------------
// Fold BN into conv weights; transpose weights; compose W12 = aw1*bn2 . pw2.
__global__ void prep_weights(
    const float* __restrict__ pw1, const float* __restrict__ pb1,
    const float* __restrict__ g1, const float* __restrict__ bb1,
    const float* __restrict__ m1, const float* __restrict__ v1,
    const float* __restrict__ pw2,
    const float* __restrict__ aw1, const float* __restrict__ ab1,
    const float* __restrict__ g2, const float* __restrict__ bb2,
    const float* __restrict__ m2, const float* __restrict__ v2,
    const float* __restrict__ aw2,
    float* __restrict__ w1f, float* __restrict__ b1f, float* __restrict__ ab1f,
    float* __restrict__ pw2t, float* __restrict__ aw1t, float* __restrict__ aw2t,
    float* __restrict__ W12t) {
  int tid = threadIdx.x;
  if (tid < 64) {
    float s = g1[tid] * rsqrtf(v1[tid] + 1e-5f);
    w1f[tid * 4 + 0] = pw1[tid * 3 + 0] * s;
    w1f[tid * 4 + 1] = pw1[tid * 3 + 1] * s;
    w1f[tid * 4 + 2] = pw1[tid * 3 + 2] * s;
    w1f[tid * 4 + 3] = 0.f;
    b1f[tid] = (pb1[tid] - m1[tid]) * s + bb1[tid];
    float s2 = g2[tid] * rsqrtf(v2[tid] + 1e-5f);
    ab1f[tid] = (ab1[tid] - m2[tid]) * s2 + bb2[tid];
  }
  // pw2t[i][c] = pw2[c][i]   (64 x 256)
  for (int x = tid; x < 64 * 256; x += 256) {
    int i = x >> 8, c = x & 255;
    pw2t[x] = pw2[c * 64 + i];
  }
  // aw1t[c][d] = aw1[d][c] * s2[d]   (256 x 64), bn2 folded
  for (int x = tid; x < 256 * 64; x += 256) {
    int c = x >> 6, d = x & 63;
    float s2 = g2[d] * rsqrtf(v2[d] + 1e-5f);
    aw1t[x] = aw1[d * 256 + c] * s2;
  }
  // aw2t[i][o] = aw2[o][i]   (64 x 260 padded)
  for (int x = tid; x < 64 * OC; x += 256) {
    int i = x / OC, o = x % OC;
    aw2t[i * 260 + o] = aw2[o * 64 + i];
  }
  // W12t[i][d] = sum_c pw2[c][i] * aw1[d][c] * s2[d]   (64 x 64)
  for (int x = tid; x < 64 * 64; x += 256) {
    int i = x >> 6, d = x & 63;
    float s2 = g2[d] * rsqrtf(v2[d] + 1e-5f);
    float s = 0.f;
    for (int c = 0; c < 256; ++c) s += pw2[c * 64 + i] * aw1[d * 256 + c];
    W12t[x] = s * s2;
  }
}

// ---------------------------------------------------------------------------
// FPS v2: 1 block/batch, 512 threads, 8 pts/thread. Cross-lane argmax via
// DPP (VALU-speed, no LDS-pipe shuffles); per-wave results in LDS slots
// (double-buffered by step parity), redundant 8-entry scan; 1 barrier/step.
__global__ __launch_bounds__(512) void fps_kernel(const float* __restrict__ verts,
                                                  int* __restrict__ fps_idx) {
  int b = blockIdx.x;
  int tid = threadIdx.x;
  __shared__ float lx[NN], ly[NN], lz[NN];
  __shared__ unsigned long long wres[2][8];
  const float* vb = verts + (size_t)b * 3 * NN;
  float px[8], py[8], pz[8], dist[8];
#pragma unroll
  for (int r = 0; r < 8; ++r) {
    int j = tid + r * 512;
    px[r] = vb[j];
    py[r] = vb[NN + j];
    pz[r] = vb[2 * NN + j];
    lx[j] = px[r]; ly[j] = py[r]; lz[j] = pz[r];
    dist[r] = 1e10f;
  }
  __syncthreads();
  int far = 0;
  for (int s = 0; s < MM; ++s) {
    if (tid == 0) fps_idx[b * MM + s] = far;
    if (s == MM - 1) break;
    float cx = lx[far], cy = ly[far], cz = lz[far];
    float bestv = -1.0f;
    int bestj = 0;
#pragma unroll
    for (int r = 0; r < 8; ++r) {
      float dx = px[r] - cx, dy = py[r] - cy, dz = pz[r] - cz;
      float d = dx * dx + dy * dy + dz * dz;
      dist[r] = fminf(dist[r], d);
      if (dist[r] > bestv) { bestv = dist[r]; bestj = tid + r * 512; }
    }
    int di = __float_as_int(bestv);  // dist >= 0 -> signed-int compare OK
    int ii = bestj;
    // max-reduce (dist, idx) pair across 64 lanes; tie -> smaller idx.
    // old = own value so invalid-source lanes are self-compares (no-ops).
#define FPS_DPP(CTRL)                                                      \
    {                                                                      \
      int od = __builtin_amdgcn_update_dpp(di, di, CTRL, 0xF, 0xF, false); \
      int oi = __builtin_amdgcn_update_dpp(ii, ii, CTRL, 0xF, 0xF, false); \
      bool bt = (od > di) || (od == di && oi < ii);                        \
      di = bt ? od : di;                                                   \
      ii = bt ? oi : ii;                                                   \
    }
    FPS_DPP(0x111)  // row_shr:1
    FPS_DPP(0x112)  // row_shr:2
    FPS_DPP(0x114)  // row_shr:4
    FPS_DPP(0x118)  // row_shr:8
    FPS_DPP(0x142)  // row_bcast:15
    FPS_DPP(0x143)  // row_bcast:31
#undef FPS_DPP
    if ((tid & 63) == 63)
      wres[s & 1][tid >> 6] =
          ((unsigned long long)(unsigned)di << 12) | (unsigned long long)(4095 - ii);
    __syncthreads();
    unsigned long long best = wres[s & 1][0];
#pragma unroll
    for (int w = 1; w < 8; ++w) {
      unsigned long long v = wres[s & 1][w];
      if (v > best) best = v;
    }
    far = 4095 - (int)(best & 0xFFFull);
  }
}

// ---------------------------------------------------------------------------
// KNN top-16: one wave per key point (unchanged, verified in round 0).
__global__ __launch_bounds__(64) void knn_kernel(const float* __restrict__ verts,
                                                 const int* __restrict__ fps_idx,
                                                 int* __restrict__ knn_idx) {
  int blk = blockIdx.x;
  int b = blk >> 10;
  int m = blk & 1023;
  int lane = threadIdx.x;
  __shared__ float dbuf[64 * 65];
  const float* vb = verts + (size_t)b * 3 * NN;
  int jm = fps_idx[b * MM + m];
  float kx = vb[jm], ky = vb[NN + jm], kz = vb[2 * NN + jm];
  float kn = kx * kx + ky * ky + kz * kz;
  float v1 = INFINITY, v2 = INFINITY;
  int i1 = -1, i2 = -1;
  for (int t = 0; t < 64; ++t) {
    int j = t * 64 + lane;
    float x = vb[j], y = vb[NN + j], z = vb[2 * NN + j];
    float xn = x * x + y * y + z * z;
    float d = kn + xn - 2.0f * (kx * x + ky * y + kz * z);
    dbuf[lane * 65 + t] = d;
    if (d < v1) { v2 = v1; i2 = i1; v1 = d; i1 = j; }
    else if (d < v2) { v2 = d; i2 = j; }
  }
  for (int it = 0; it < KNB; ++it) {
    float rv = v1;
    int ri = i1;
#pragma unroll
    for (int off = 32; off >= 1; off >>= 1) {
      float ov = __shfl_down(rv, off, 64);
      int oi = __shfl_down(ri, off, 64);
      if (ov < rv || (ov == rv && oi < ri)) { rv = ov; ri = oi; }
    }
    ri = __shfl(ri, 0, 64);
    if (lane == 0) knn_idx[(size_t)(b * MM + m) * KNB + it] = ri;
    if (i1 == ri) {
      dbuf[lane * 65 + (ri >> 6)] = INFINITY;
      v1 = v2; i1 = i2;
      v2 = INFINITY; i2 = -1;
      if (i1 < 0) {
        v1 = INFINITY; v2 = INFINITY; i1 = -1; i2 = -1;
        for (int t = 0; t < 64; ++t) {
          float d = dbuf[lane * 65 + t];
          int j = t * 64 + lane;
          if (d < v1) { v2 = v1; i2 = i1; v1 = d; i1 = j; }
          else if (d < v2) { v2 = d; i2 = j; }
        }
      }
    }
  }
}

// ---------------------------------------------------------------------------
// G2[b][n][d] = sum_c aw1t[c][d] * fm[b][c][n]  — dense tiled GEMM, fm is
// already [k=c][n] so no transpose needed. 64n x 64d tile, 4x4 per thread.
__global__ __launch_bounds__(256) void g2_kernel(const float* __restrict__ fm,
                                                 const float* __restrict__ aw1t,
                                                 float* __restrict__ G2) {
  __shared__ __attribute__((aligned(16))) float a_l[64][68];
  __shared__ __attribute__((aligned(16))) float b_l[64][68];
  int b = blockIdx.y;
  int n0 = blockIdx.x * 64;
  int tid = threadIdx.x;
  int rr = tid >> 4, q4 = tid & 15;
  float acc[4][4];
#pragma unroll
  for (int q = 0; q < 4; ++q)
#pragma unroll
    for (int x = 0; x < 4; ++x) acc[q][x] = 0.f;
  for (int c0 = 0; c0 < 256; c0 += 64) {
    __syncthreads();
#pragma unroll
    for (int rep = 0; rep < 4; ++rep) {
      int cc = rr + rep * 16;
      *(float4*)&a_l[cc][q4 * 4] =
          *(const float4*)&fm[((size_t)b * CC + c0 + cc) * NN + n0 + q4 * 4];
      *(float4*)&b_l[cc][q4 * 4] = *(const float4*)&aw1t[(c0 + cc) * 64 + q4 * 4];
    }
    __syncthreads();
#pragma unroll 8
    for (int kk = 0; kk < 64; ++kk) {
      float4 a4 = *(const float4*)&a_l[kk][rr * 4];
      float4 b4 = *(const float4*)&b_l[kk][q4 * 4];
      float av[4] = {a4.x, a4.y, a4.z, a4.w};
#pragma unroll
      for (int q = 0; q < 4; ++q) {
        acc[q][0] += av[q] * b4.x;
        acc[q][1] += av[q] * b4.y;
        acc[q][2] += av[q] * b4.z;
        acc[q][3] += av[q] * b4.w;
      }
    }
  }
#pragma unroll
  for (int q = 0; q < 4; ++q)
    *(float4*)&G2[((size_t)b * NN + n0 + rr * 4 + q) * 64 + q4 * 4] =
        make_float4(acc[q][0], acc[q][1], acc[q][2], acc[q][3]);
}

// ---------------------------------------------------------------------------
// Fused per-(b,m): h(16x64) -> vm / G2-gather / W12.h -> h2(16x64) ->
// logits(259) via per-thread weight column -> in-register softmax ->
// aggregation.  out_feat[c] = pb2[c] + sum_k w.gf + sum_i pw2t[i][c].hbar_c[i]
// (uses sum_k softmax = 1; t never materialized).
__global__ __launch_bounds__(256, 3) void fuse_kernel(
    const float* __restrict__ verts, const float* __restrict__ fm_t,
    const float* __restrict__ G2,
    const int* __restrict__ fpsi, const int* __restrict__ knni,
    const float* __restrict__ w1f, const float* __restrict__ b1f,
    const float* __restrict__ ab1f, const float* __restrict__ aw1t,
    const float* __restrict__ W12t, const float* __restrict__ pw2t,
    const float* __restrict__ pb2, const float* __restrict__ aw2t,
    const float* __restrict__ ab2, float* __restrict__ out) {
  int bm = blockIdx.x;
  int b = bm >> 10, m = bm & 1023;
  int tid = threadIdx.x;

  __shared__ __attribute__((aligned(16))) float kfpb[256];
  __shared__ __attribute__((aligned(16))) float pb2_l[256];
  __shared__ __attribute__((aligned(16))) float gp[3][16];
  __shared__ __attribute__((aligned(16))) float kp[4];
  __shared__ int kidx[16];
  __shared__ __attribute__((aligned(16))) float W12_l[64][68];
  __shared__ __attribute__((aligned(16))) float gf_l[16][256];
  __shared__ __attribute__((aligned(16))) float h_l[16][68];
  __shared__ __attribute__((aligned(16))) float hT_l[64][20];
  __shared__ __attribute__((aligned(16))) float vmp[4][64];
  __shared__ __attribute__((aligned(16))) float vm_l[64];
  __shared__ __attribute__((aligned(16))) float h2_l[16][68];

  const float* vb = verts + (size_t)b * 3 * NN;
  const float* fb = fm_t + (size_t)b * NN * CC;
  int jm = fpsi[bm];
  if (tid < 16) kidx[tid] = knni[(size_t)bm * 16 + tid];
  kfpb[tid] = fb[(size_t)jm * CC + tid] + pb2[tid];
  pb2_l[tid] = pb2[tid];
  if (tid < 3) kp[tid] = vb[tid * NN + jm];
  __syncthreads();

  // ---- stage: gp gather, W12 -> LDS, gf rows -> LDS
  if (tid < 48) {
    int c = tid >> 4, k = tid & 15;
    gp[c][k] = vb[c * NN + kidx[k]];
  }
  {
    int i = tid >> 4, d4 = tid & 15;
#pragma unroll
    for (int rep = 0; rep < 4; ++rep)
      *(float4*)&W12_l[i + rep * 16][d4 * 4] =
          *(const float4*)&W12t[(i + rep * 16) * 64 + d4 * 4];
  }
  {
    int k = tid >> 4;
    const float* grow = fb + (size_t)kidx[k] * CC;
#pragma unroll
    for (int rep = 0; rep < 4; ++rep) {
      int c4 = (tid & 15) + rep * 16;
      *(float4*)&gf_l[k][c4 * 4] = *(const float4*)&grow[c4 * 4];
    }
  }
  __syncthreads();

  // ---- h (leaky-relu conv1) + vm partials (aw1t . (kf+pb2))
  {
    int d = tid & 63, part = tid >> 6;
    float wd0 = w1f[d * 4 + 0], wd1 = w1f[d * 4 + 1], wd2 = w1f[d * 4 + 2];
    float bd = b1f[d];
#pragma unroll
    for (int j = 0; j < 4; ++j) {
      int k = part * 4 + j;
      float hv = wd0 * (kp[0] - gp[0][k]) + wd1 * (kp[1] - gp[1][k]) +
                 wd2 * (kp[2] - gp[2][k]) + bd;
      hv = (hv > 0.f) ? hv : 0.2f * hv;
      h_l[k][d] = hv;
      hT_l[d][k] = hv;
    }
    float acc = 0.f;
    for (int cc = 0; cc < 64; ++cc) {
      int c = part * 64 + cc;
      acc += aw1t[c * 64 + d] * kfpb[c];
    }
    vmp[part][d] = acc;
  }
  __syncthreads();
  if (tid < 64)
    vm_l[tid] = vmp[0][tid] + vmp[1][tid] + vmp[2][tid] + vmp[3][tid] + ab1f[tid];
  __syncthreads();

  // ---- h2[k][d] = lrelu(vm[d] - G2[j_k][d] + sum_i W12[i][d] h[k][i])
  {
    int k = tid >> 4, dq = tid & 15;
    float a0 = 0.f, a1 = 0.f, a2 = 0.f, a3 = 0.f;
#pragma unroll 4
    for (int i = 0; i < 64; ++i) {
      float hv = h_l[k][i];
      float4 w4 = *(const float4*)&W12_l[i][dq * 4];
      a0 += hv * w4.x; a1 += hv * w4.y; a2 += hv * w4.z; a3 += hv * w4.w;
    }
    float4 g4 = *(const float4*)&G2[((size_t)b * NN + kidx[k]) * 64 + dq * 4];
    float4 v4 = *(const float4*)&vm_l[dq * 4];
    float r0 = v4.x - g4.x + a0;
    float r1 = v4.y - g4.y + a1;
    float r2 = v4.z - g4.z + a2;
    float r3 = v4.w - g4.w + a3;
    r0 = (r0 > 0.f) ? r0 : 0.2f * r0;
    r1 = (r1 > 0.f) ? r1 : 0.2f * r1;
    r2 = (r2 > 0.f) ? r2 : 0.2f * r2;
    r3 = (r3 > 0.f) ? r3 : 0.2f * r3;
    *(float4*)&h2_l[k][dq * 4] = make_float4(r0, r1, r2, r3);
  }
  __syncthreads();

  // ---- logits (thread -> output column o = tid+3), in-register softmax,
  //      per-thread pe reconstruction and aggregation.
  {
    int o = tid + 3;
    float wcol[64];
#pragma unroll
    for (int i = 0; i < 64; ++i) wcol[i] = aw2t[i * 260 + o];
    float lg[16];
    float bias = ab2[o];
#pragma unroll
    for (int k = 0; k < 16; ++k) {
      float s = bias;
#pragma unroll
      for (int i4 = 0; i4 < 16; ++i4) {
        float4 h4 = *(const float4*)&h2_l[k][i4 * 4];
        s += wcol[i4 * 4 + 0] * h4.x + wcol[i4 * 4 + 1] * h4.y +
             wcol[i4 * 4 + 2] * h4.z + wcol[i4 * 4 + 3] * h4.w;
      }
      lg[k] = s;
    }
    float mx = lg[0];
#pragma unroll
    for (int k = 1; k < 16; ++k) mx = fmaxf(mx, lg[k]);
    float w[16], sum = 0.f;
#pragma unroll
    for (int k = 0; k < 16; ++k) { w[k] = __expf(lg[k] - mx); sum += w[k]; }
    float inv = 1.f / sum;
#pragma unroll
    for (int k = 0; k < 16; ++k) w[k] *= inv;

    // pe[k] = sum_i pw2t[i][c] * h[k][i]   (c = tid)
    float pe[16];
#pragma unroll
    for (int k = 0; k < 16; ++k) pe[k] = 0.f;
    const float* pcol = pw2t + tid;
#pragma unroll 2
    for (int i = 0; i < 64; ++i) {
      float p = pcol[i * 256];
      float4 ha = *(const float4*)&hT_l[i][0];
      float4 hb = *(const float4*)&hT_l[i][4];
      float4 hc = *(const float4*)&hT_l[i][8];
      float4 hd = *(const float4*)&hT_l[i][12];
      pe[0] += p * ha.x;  pe[1] += p * ha.y;  pe[2] += p * ha.z;  pe[3] += p * ha.w;
      pe[4] += p * hb.x;  pe[5] += p * hb.y;  pe[6] += p * hb.z;  pe[7] += p * hb.w;
      pe[8] += p * hc.x;  pe[9] += p * hc.y;  pe[10] += p * hc.z; pe[11] += p * hc.w;
      pe[12] += p * hd.x; pe[13] += p * hd.y; pe[14] += p * hd.z; pe[15] += p * hd.w;
    }
    float pea = 0.f, gfa = 0.f;
#pragma unroll
    for (int k = 0; k < 16; ++k) {
      pea += w[k] * pe[k];
      gfa += w[k] * gf_l[k][tid];
    }
    out[((size_t)b * OC + o) * MM + m] = pb2_l[tid] + pea + gfa;

    // xyz outputs: threads 0..2 run a second logits/softmax pass for o=0..2
    if (tid < 3) {
#pragma unroll
      for (int i = 0; i < 64; ++i) wcol[i] = aw2t[i * 260 + tid];
      float bias2 = ab2[tid];
#pragma unroll
      for (int k = 0; k < 16; ++k) {
        float s = bias2;
#pragma unroll
        for (int i4 = 0; i4 < 16; ++i4) {
          float4 h4 = *(const float4*)&h2_l[k][i4 * 4];
          s += wcol[i4 * 4 + 0] * h4.x + wcol[i4 * 4 + 1] * h4.y +
               wcol[i4 * 4 + 2] * h4.z + wcol[i4 * 4 + 3] * h4.w;
        }
        lg[k] = s;
      }
      float mx2 = lg[0];
#pragma unroll
      for (int k = 1; k < 16; ++k) mx2 = fmaxf(mx2, lg[k]);
      float sum2 = 0.f;
#pragma unroll
      for (int k = 0; k < 16; ++k) { w[k] = __expf(lg[k] - mx2); sum2 += w[k]; }
      float inv2 = 1.f / sum2;
      float a2 = 0.f;
#pragma unroll
      for (int k = 0; k < 16; ++k) a2 += w[k] * inv2 * gp[tid][k];
      out[((size_t)b * OC + tid) * MM + m] = a2;
    }
  }
}

// ---------------------------------------------------------------------------
extern "C" void kernel_launch(void* const* d_in, const int* in_sizes, int n_in,
                              void* d_out, int out_size, void* d_ws, size_t ws_size,
                              hipStream_t stream) {
  (void)in_sizes; (void)n_in; (void)out_size; (void)ws_size;
  const float* verts = (const float*)d_in[0];
  const float* fm = (const float*)d_in[1];
  const float* pw1 = (const float*)d_in[2];
  const float* pb1 = (const float*)d_in[3];
  const float* g1 = (const float*)d_in[4];
  const float* bb1 = (const float*)d_in[5];
  const float* m1 = (const float*)d_in[6];
  const float* v1 = (const float*)d_in[7];
  const float* pw2 = (const float*)d_in[8];
  const float* pb2 = (const float*)d_in[9];
  const float* aw1 = (const float*)d_in[10];
  const float* ab1 = (const float*)d_in[11];
  const float* g2 = (const float*)d_in[12];
  const float* bb2 = (const float*)d_in[13];
  const float* m2 = (const float*)d_in[14];
  const float* v2 = (const float*)d_in[15];
  const float* aw2 = (const float*)d_in[16];
  const float* ab2 = (const float*)d_in[17];
  float* out = (float*)d_out;

  char* ws = (char*)d_ws;
  float* fm_t = (float*)ws;                               // 33,554,432 B
  float* G2 = (float*)(ws + 33554432);                    //  8,388,608 B
  int* fpsi = (int*)(ws + 41943040);                      //     32,768 B
  int* knni = (int*)(ws + 41975808);                      //    524,288 B
  float* w1f = (float*)(ws + 42500096);
  float* b1f = w1f + 256;
  float* ab1f = b1f + 64;
  float* pw2t = ab1f + 64;                                // 16384
  float* aw1t = pw2t + 64 * 256;                          // 16384
  float* aw2t = aw1t + 256 * 64;                          // 16640
  float* W12t = aw2t + 64 * 260;                          // 4096

  hipLaunchKernelGGL(transpose_fm, dim3(64, 4, 8), dim3(64, 4), 0, stream, fm, fm_t);
  hipLaunchKernelGGL(prep_weights, dim3(1), dim3(256), 0, stream,
                     pw1, pb1, g1, bb1, m1, v1, pw2, aw1, ab1, g2, bb2, m2, v2,
                     aw2, w1f, b1f, ab1f, pw2t, aw1t, aw2t, W12t);
  hipLaunchKernelGGL(fps_kernel, dim3(8), dim3(512), 0, stream, verts, fpsi);
  hipLaunchKernelGGL(knn_kernel, dim3(8192), dim3(64), 0, stream, verts, fpsi, knni);
  hipLaunchKernelGGL(g2_kernel, dim3(64, 8), dim3(256), 0, stream, fm, aw1t, G2);
  hipLaunchKernelGGL(fuse_kernel, dim3(8192), dim3(256), 0, stream,
                     verts, fm_t, G2, fpsi, knni, w1f, b1f, ab1f, aw1t, W12t,
                     pw2t, pb2, aw2t, ab2, out);
}

// Round 3
// 1455.316 us; speedup vs baseline: 4.6010x; 4.6010x over previous
//
#include <hip/hip_runtime.h>
#include <math.h>

#define BB 8
#define NN 4096
#define CC 256
#define DD 64
#define MM 1024
#define KNB 16
#define OC 259

// ---------------------------------------------------------------------------
// Transpose feature_map (B,C,N) -> (B,N,C) for coalesced per-point gathers.
__global__ __launch_bounds__(256) void transpose_fm(const float* __restrict__ fm,
                                                    float* __restrict__ fm_t) {
  __shared__ float tile[64][65];
  int b = blockIdx.z;
  int n0 = blockIdx.x * 64;
  int c0 = blockIdx.y * 64;
  const float* src = fm + (size_t)b * CC * NN;
  float* dst = fm_t + (size_t)b * NN * CC;
  int tx = threadIdx.x, ty = threadIdx.y;
  for (int r = ty; r < 64; r += 4)
    tile[r][tx] = src[(size_t)(c0 + r) * NN + n0 + tx];
  __syncthreads();
  for (int r = ty; r < 64; r += 4)
    dst[(size_t)(n0 + r) * CC + c0 + tx] = tile[tx][r];
}

// ---------------------------------------------------------------------------
// Small weight prep: BN folds + transposes (no W12 here — it gets its own grid).
__global__ void prep_small(
    const float* __restrict__ pw1, const float* __restrict__ pb1,
    const float* __restrict__ g1, const float* __restrict__ bb1,
    const float* __restrict__ m1, const float* __restrict__ v1,
    const float* __restrict__ pw2,
    const float* __restrict__ aw1, const float* __restrict__ ab1,
    const float* __restrict__ g2, const float* __restrict__ bb2,
    const float* __restrict__ m2, const float* __restrict__ v2,
    const float* __restrict__ aw2,
    float* __restrict__ w1f, float* __restrict__ b1f, float* __restrict__ ab1f,
    float* __restrict__ pw2t, float* __restrict__ aw1t, float* __restrict__ aw2t) {
  int tid = threadIdx.x;
  if (tid < 64) {
    float s = g1[tid] * rsqrtf(v1[tid] + 1e-5f);
    w1f[tid * 4 + 0] = pw1[tid * 3 + 0] * s;
    w1f[tid * 4 + 1] = pw1[tid * 3 + 1] * s;
    w1f[tid * 4 + 2] = pw1[tid * 3 + 2] * s;
    w1f[tid * 4 + 3] = 0.f;
    b1f[tid] = (pb1[tid] - m1[tid]) * s + bb1[tid];
    float s2 = g2[tid] * rsqrtf(v2[tid] + 1e-5f);
    ab1f[tid] = (ab1[tid] - m2[tid]) * s2 + bb2[tid];
  }
  for (int x = tid; x < 64 * 256; x += 256) {   // pw2t[i][c] = pw2[c][i]
    int i = x >> 8, c = x & 255;
    pw2t[x] = pw2[c * 64 + i];
  }
  for (int x = tid; x < 256 * 64; x += 256) {   // aw1t[c][d] = aw1[d][c]*s2[d]
    int c = x >> 6, d = x & 63;
    float s2 = g2[d] * rsqrtf(v2[d] + 1e-5f);
    aw1t[x] = aw1[d * 256 + c] * s2;
  }
  for (int x = tid; x < 64 * OC; x += 256) {    // aw2t[i][o] = aw2[o][i]
    int i = x / OC, o = x % OC;
    aw2t[i * 260 + o] = aw2[o * 64 + i];
  }
}

// W12t[i][d] = sum_c pw2[c][i]*aw1[d][c]*s2[d].  16 blocks x 256 threads;
// d is wave-uniform (s_load for aw1 row), pw2 reads coalesced over i.
__global__ __launch_bounds__(256) void w12_kernel(
    const float* __restrict__ pw2, const float* __restrict__ aw1,
    const float* __restrict__ g2, const float* __restrict__ v2,
    float* __restrict__ W12t) {
  int i = threadIdx.x & 63;
  int d = blockIdx.x * 4 + (threadIdx.x >> 6);
  float s2 = g2[d] * rsqrtf(v2[d] + 1e-5f);
  const float* arow = aw1 + d * 256;
  float s = 0.f;
#pragma unroll 4
  for (int c = 0; c < 256; ++c) s += pw2[c * 64 + i] * arow[c];
  W12t[i * 64 + d] = s * s2;
}

// ---------------------------------------------------------------------------
// FPS: 1 block/batch, 512 threads, 8 pts/thread, DPP wave argmax,
// double-buffered per-wave LDS slots, 1 barrier/step.
__global__ __launch_bounds__(512) void fps_kernel(const float* __restrict__ verts,
                                                  int* __restrict__ fps_idx) {
  int b = blockIdx.x;
  int tid = threadIdx.x;
  __shared__ float lx[NN], ly[NN], lz[NN];
  __shared__ unsigned long long wres[2][8];
  const float* vb = verts + (size_t)b * 3 * NN;
  float px[8], py[8], pz[8], dist[8];
#pragma unroll
  for (int r = 0; r < 8; ++r) {
    int j = tid + r * 512;
    px[r] = vb[j];
    py[r] = vb[NN + j];
    pz[r] = vb[2 * NN + j];
    lx[j] = px[r]; ly[j] = py[r]; lz[j] = pz[r];
    dist[r] = 1e10f;
  }
  __syncthreads();
  int far = 0;
  for (int s = 0; s < MM; ++s) {
    if (tid == 0) fps_idx[b * MM + s] = far;
    if (s == MM - 1) break;
    float cx = lx[far], cy = ly[far], cz = lz[far];
    float bestv = -1.0f;
    int bestj = 0;
#pragma unroll
    for (int r = 0; r < 8; ++r) {
      float dx = px[r] - cx, dy = py[r] - cy, dz = pz[r] - cz;
      float d = dx * dx + dy * dy + dz * dz;
      dist[r] = fminf(dist[r], d);
      if (dist[r] > bestv) { bestv = dist[r]; bestj = tid + r * 512; }
    }
    int di = __float_as_int(bestv);
    int ii = bestj;
#define FPS_DPP(CTRL)                                                      \
    {                                                                      \
      int od = __builtin_amdgcn_update_dpp(di, di, CTRL, 0xF, 0xF, false); \
      int oi = __builtin_amdgcn_update_dpp(ii, ii, CTRL, 0xF, 0xF, false); \
      bool bt = (od > di) || (od == di && oi < ii);                        \
      di = bt ? od : di;                                                   \
      ii = bt ? oi : ii;                                                   \
    }
    FPS_DPP(0x111)
    FPS_DPP(0x112)
    FPS_DPP(0x114)
    FPS_DPP(0x118)
    FPS_DPP(0x142)
    FPS_DPP(0x143)
#undef FPS_DPP
    if ((tid & 63) == 63)
      wres[s & 1][tid >> 6] =
          ((unsigned long long)(unsigned)di << 12) | (unsigned long long)(4095 - ii);
    __syncthreads();
    unsigned long long best = wres[s & 1][0];
#pragma unroll
    for (int w = 1; w < 8; ++w) {
      unsigned long long v = wres[s & 1][w];
      if (v > best) best = v;
    }
    far = 4095 - (int)(best & 0xFFFull);
  }
}

// ---------------------------------------------------------------------------
// KNN top-16: one wave per key point (verified).
__global__ __launch_bounds__(64) void knn_kernel(const float* __restrict__ verts,
                                                 const int* __restrict__ fps_idx,
                                                 int* __restrict__ knn_idx) {
  int blk = blockIdx.x;
  int b = blk >> 10;
  int m = blk & 1023;
  int lane = threadIdx.x;
  __shared__ float dbuf[64 * 65];
  const float* vb = verts + (size_t)b * 3 * NN;
  int jm = fps_idx[b * MM + m];
  float kx = vb[jm], ky = vb[NN + jm], kz = vb[2 * NN + jm];
  float kn = kx * kx + ky * ky + kz * kz;
  float v1 = INFINITY, v2 = INFINITY;
  int i1 = -1, i2 = -1;
  for (int t = 0; t < 64; ++t) {
    int j = t * 64 + lane;
    float x = vb[j], y = vb[NN + j], z = vb[2 * NN + j];
    float xn = x * x + y * y + z * z;
    float d = kn + xn - 2.0f * (kx * x + ky * y + kz * z);
    dbuf[lane * 65 + t] = d;
    if (d < v1) { v2 = v1; i2 = i1; v1 = d; i1 = j; }
    else if (d < v2) { v2 = d; i2 = j; }
  }
  for (int it = 0; it < KNB; ++it) {
    float rv = v1;
    int ri = i1;
#pragma unroll
    for (int off = 32; off >= 1; off >>= 1) {
      float ov = __shfl_down(rv, off, 64);
      int oi = __shfl_down(ri, off, 64);
      if (ov < rv || (ov == rv && oi < ri)) { rv = ov; ri = oi; }
    }
    ri = __shfl(ri, 0, 64);
    if (lane == 0) knn_idx[(size_t)(b * MM + m) * KNB + it] = ri;
    if (i1 == ri) {
      dbuf[lane * 65 + (ri >> 6)] = INFINITY;
      v1 = v2; i1 = i2;
      v2 = INFINITY; i2 = -1;
      if (i1 < 0) {
        v1 = INFINITY; v2 = INFINITY; i1 = -1; i2 = -1;
        for (int t = 0; t < 64; ++t) {
          float d = dbuf[lane * 65 + t];
          int j = t * 64 + lane;
          if (d < v1) { v2 = v1; i2 = i1; v1 = d; i1 = j; }
          else if (d < v2) { v2 = d; i2 = j; }
        }
      }
    }
  }
}

// ---------------------------------------------------------------------------
// G2[b][n][d] = sum_c aw1t[c][d] * fm[b][c][n]  — tiled fp32 GEMM.
__global__ __launch_bounds__(256) void g2_kernel(const float* __restrict__ fm,
                                                 const float* __restrict__ aw1t,
                                                 float* __restrict__ G2) {
  __shared__ __attribute__((aligned(16))) float a_l[64][68];
  __shared__ __attribute__((aligned(16))) float b_l[64][68];
  int b = blockIdx.y;
  int n0 = blockIdx.x * 64;
  int tid = threadIdx.x;
  int rr = tid >> 4, q4 = tid & 15;
  float acc[4][4];
#pragma unroll
  for (int q = 0; q < 4; ++q)
#pragma unroll
    for (int x = 0; x < 4; ++x) acc[q][x] = 0.f;
  for (int c0 = 0; c0 < 256; c0 += 64) {
    __syncthreads();
#pragma unroll
    for (int rep = 0; rep < 4; ++rep) {
      int cc = rr + rep * 16;
      *(float4*)&a_l[cc][q4 * 4] =
          *(const float4*)&fm[((size_t)b * CC + c0 + cc) * NN + n0 + q4 * 4];
      *(float4*)&b_l[cc][q4 * 4] = *(const float4*)&aw1t[(c0 + cc) * 64 + q4 * 4];
    }
    __syncthreads();
#pragma unroll 8
    for (int kk = 0; kk < 64; ++kk) {
      float4 a4 = *(const float4*)&a_l[kk][rr * 4];
      float4 b4 = *(const float4*)&b_l[kk][q4 * 4];
      float av[4] = {a4.x, a4.y, a4.z, a4.w};
#pragma unroll
      for (int q = 0; q < 4; ++q) {
        acc[q][0] += av[q] * b4.x;
        acc[q][1] += av[q] * b4.y;
        acc[q][2] += av[q] * b4.z;
        acc[q][3] += av[q] * b4.w;
      }
    }
  }
#pragma unroll
  for (int q = 0; q < 4; ++q)
    *(float4*)&G2[((size_t)b * NN + n0 + rr * 4 + q) * 64 + q4 * 4] =
        make_float4(acc[q][0], acc[q][1], acc[q][2], acc[q][3]);
}

// ---------------------------------------------------------------------------
// Fused per-(b,m). Register-frugal: max per-thread array = 16 floats.
// Stage D reads h2/h via transposed LDS rows (pad 20 -> 16B-aligned b128,
// wave-broadcast). gf prefetched into regs before logits loop.
__global__ __launch_bounds__(256, 3) void fuse_kernel(
    const float* __restrict__ verts, const float* __restrict__ fm_t,
    const float* __restrict__ G2,
    const int* __restrict__ fpsi, const int* __restrict__ knni,
    const float* __restrict__ w1f, const float* __restrict__ b1f,
    const float* __restrict__ ab1f, const float* __restrict__ aw1t,
    const float* __restrict__ W12t, const float* __restrict__ pw2t,
    const float* __restrict__ pb2, const float* __restrict__ aw2t,
    const float* __restrict__ ab2, float* __restrict__ out) {
  int bm = blockIdx.x;
  int b = bm & 7, m = bm >> 3;  // batch -> XCD pinning
  int tid = threadIdx.x;

  __shared__ __attribute__((aligned(16))) float kfpb[256];
  __shared__ __attribute__((aligned(16))) float pb2_l[256];
  __shared__ __attribute__((aligned(16))) float gp[3][16];
  __shared__ __attribute__((aligned(16))) float kp[4];
  __shared__ int kidx[16];
  __shared__ __attribute__((aligned(16))) float W12_l[64][68];
  __shared__ __attribute__((aligned(16))) float h_l[16][68];
  __shared__ __attribute__((aligned(16))) float hT_l[64][20];
  __shared__ __attribute__((aligned(16))) float h2T_l[64][20];
  __shared__ __attribute__((aligned(16))) float vmp[4][64];
  __shared__ __attribute__((aligned(16))) float vm_l[64];

  const float* vb = verts + (size_t)b * 3 * NN;
  const float* fb = fm_t + (size_t)b * NN * CC;
  int jm = fpsi[b * MM + m];
  if (tid < 16) kidx[tid] = knni[((size_t)b * MM + m) * 16 + tid];
  kfpb[tid] = fb[(size_t)jm * CC + tid] + pb2[tid];
  pb2_l[tid] = pb2[tid];
  if (tid < 3) kp[tid] = vb[tid * NN + jm];
  __syncthreads();

  // gp gather + W12 staging + vm partials
  if (tid < 48) {
    int c = tid >> 4, k = tid & 15;
    gp[c][k] = vb[c * NN + kidx[k]];
  }
  {
    int i = tid >> 4, d4 = tid & 15;
#pragma unroll
    for (int rep = 0; rep < 4; ++rep)
      *(float4*)&W12_l[i + rep * 16][d4 * 4] =
          *(const float4*)&W12t[(i + rep * 16) * 64 + d4 * 4];
  }
  {
    int d = tid & 63, part = tid >> 6;
    float acc = 0.f;
#pragma unroll 4
    for (int cc = 0; cc < 64; ++cc) {
      int c = part * 64 + cc;
      acc += aw1t[c * 64 + d] * kfpb[c];
    }
    vmp[part][d] = acc;
  }
  __syncthreads();
  if (tid < 64)
    vm_l[tid] = vmp[0][tid] + vmp[1][tid] + vmp[2][tid] + vmp[3][tid] + ab1f[tid];

  // Stage A: h = lrelu(conv1(pos_rel)); write k-major and transposed.
  {
    int d = tid & 63, part = tid >> 6;
    float wd0 = w1f[d * 4 + 0], wd1 = w1f[d * 4 + 1], wd2 = w1f[d * 4 + 2];
    float bd = b1f[d];
#pragma unroll
    for (int j = 0; j < 4; ++j) {
      int k = part * 4 + j;
      float hv = wd0 * (kp[0] - gp[0][k]) + wd1 * (kp[1] - gp[1][k]) +
                 wd2 * (kp[2] - gp[2][k]) + bd;
      hv = (hv > 0.f) ? hv : 0.2f * hv;
      h_l[k][d] = hv;
      hT_l[d][k] = hv;
    }
  }
  __syncthreads();  // h_l, hT_l, vm_l ready

  // Stage C: h2[k][d] = lrelu(vm[d] - G2[j_k][d] + sum_i W12[i][d] h[k][i])
  // thread: k = tid&15, d2 = tid>>4 (4 outputs). Writes h2 transposed.
  {
    int k = tid & 15, d2 = tid >> 4;
    float4 g4 = *(const float4*)&G2[((size_t)b * NN + kidx[k]) * 64 + d2 * 4];
    float a0 = 0.f, a1 = 0.f, a2 = 0.f, a3 = 0.f;
#pragma unroll 4
    for (int i = 0; i < 64; ++i) {
      float hv = h_l[k][i];
      float4 w4 = *(const float4*)&W12_l[i][d2 * 4];
      a0 += hv * w4.x; a1 += hv * w4.y; a2 += hv * w4.z; a3 += hv * w4.w;
    }
    float4 v4 = *(const float4*)&vm_l[d2 * 4];
    float r0 = v4.x - g4.x + a0;
    float r1 = v4.y - g4.y + a1;
    float r2 = v4.z - g4.z + a2;
    float r3 = v4.w - g4.w + a3;
    h2T_l[d2 * 4 + 0][k] = (r0 > 0.f) ? r0 : 0.2f * r0;
    h2T_l[d2 * 4 + 1][k] = (r1 > 0.f) ? r1 : 0.2f * r1;
    h2T_l[d2 * 4 + 2][k] = (r2 > 0.f) ? r2 : 0.2f * r2;
    h2T_l[d2 * 4 + 3][k] = (r3 > 0.f) ? r3 : 0.2f * r3;
  }
  __syncthreads();  // h2T ready

  // Stage D, xyz channels first (register reuse): threads 0..2, o = tid.
  if (tid < 3) {
    float lg[16];
    float bias = ab2[tid];
#pragma unroll
    for (int k = 0; k < 16; ++k) lg[k] = bias;
    const float* wp = aw2t + tid;
    for (int i = 0; i < 64; ++i) {
      float wv = wp[i * 260];
      float4 ha = *(const float4*)&h2T_l[i][0];
      float4 hb = *(const float4*)&h2T_l[i][4];
      float4 hc = *(const float4*)&h2T_l[i][8];
      float4 hd = *(const float4*)&h2T_l[i][12];
      lg[0] += wv * ha.x;  lg[1] += wv * ha.y;  lg[2] += wv * ha.z;  lg[3] += wv * ha.w;
      lg[4] += wv * hb.x;  lg[5] += wv * hb.y;  lg[6] += wv * hb.z;  lg[7] += wv * hb.w;
      lg[8] += wv * hc.x;  lg[9] += wv * hc.y;  lg[10] += wv * hc.z; lg[11] += wv * hc.w;
      lg[12] += wv * hd.x; lg[13] += wv * hd.y; lg[14] += wv * hd.z; lg[15] += wv * hd.w;
    }
    float mx = lg[0];
#pragma unroll
    for (int k = 1; k < 16; ++k) mx = fmaxf(mx, lg[k]);
    float sum = 0.f;
#pragma unroll
    for (int k = 0; k < 16; ++k) { lg[k] = __expf(lg[k] - mx); sum += lg[k]; }
    float inv = 1.f / sum;
    float a2 = 0.f;
#pragma unroll
    for (int k = 0; k < 16; ++k) a2 += lg[k] * gp[tid][k];
    out[((size_t)b * OC + tid) * MM + m] = a2 * inv;
  }

  // Stage D main: o = tid + 3 (c = tid).
  {
    int o = tid + 3;
    float gfv[16];
#pragma unroll
    for (int k = 0; k < 16; ++k)
      gfv[k] = fb[(size_t)kidx[k] * CC + tid];  // prefetched, hidden by loop
    float lg[16];
    float bias = ab2[o];
#pragma unroll
    for (int k = 0; k < 16; ++k) lg[k] = bias;
    const float* wp = aw2t + o;
#pragma unroll 4
    for (int i = 0; i < 64; ++i) {
      float wv = wp[i * 260];
      float4 ha = *(const float4*)&h2T_l[i][0];
      float4 hb = *(const float4*)&h2T_l[i][4];
      float4 hc = *(const float4*)&h2T_l[i][8];
      float4 hd = *(const float4*)&h2T_l[i][12];
      lg[0] += wv * ha.x;  lg[1] += wv * ha.y;  lg[2] += wv * ha.z;  lg[3] += wv * ha.w;
      lg[4] += wv * hb.x;  lg[5] += wv * hb.y;  lg[6] += wv * hb.z;  lg[7] += wv * hb.w;
      lg[8] += wv * hc.x;  lg[9] += wv * hc.y;  lg[10] += wv * hc.z; lg[11] += wv * hc.w;
      lg[12] += wv * hd.x; lg[13] += wv * hd.y; lg[14] += wv * hd.z; lg[15] += wv * hd.w;
    }
    float mx = lg[0];
#pragma unroll
    for (int k = 1; k < 16; ++k) mx = fmaxf(mx, lg[k]);
    float sum = 0.f;
#pragma unroll
    for (int k = 0; k < 16; ++k) { lg[k] = __expf(lg[k] - mx); sum += lg[k]; }
    float inv = 1.f / sum;
#pragma unroll
    for (int k = 0; k < 16; ++k) lg[k] *= inv;  // lg = softmax weights now
    float acc = 0.f;
#pragma unroll
    for (int k = 0; k < 16; ++k) acc += lg[k] * gfv[k];
    const float* pcol = pw2t + tid;
#pragma unroll 4
    for (int i = 0; i < 64; ++i) {
      float p = pcol[i * 256];
      float4 ha = *(const float4*)&hT_l[i][0];
      float4 hb = *(const float4*)&hT_l[i][4];
      float4 hc = *(const float4*)&hT_l[i][8];
      float4 hd = *(const float4*)&hT_l[i][12];
      float hw = lg[0] * ha.x + lg[1] * ha.y + lg[2] * ha.z + lg[3] * ha.w +
                 lg[4] * hb.x + lg[5] * hb.y + lg[6] * hb.z + lg[7] * hb.w +
                 lg[8] * hc.x + lg[9] * hc.y + lg[10] * hc.z + lg[11] * hc.w +
                 lg[12] * hd.x + lg[13] * hd.y + lg[14] * hd.z + lg[15] * hd.w;
      acc += p * hw;
    }
    out[((size_t)b * OC + o) * MM + m] = pb2_l[tid] + acc;
  }
}

// ---------------------------------------------------------------------------
extern "C" void kernel_launch(void* const* d_in, const int* in_sizes, int n_in,
                              void* d_out, int out_size, void* d_ws, size_t ws_size,
                              hipStream_t stream) {
  (void)in_sizes; (void)n_in; (void)out_size; (void)ws_size;
  const float* verts = (const float*)d_in[0];
  const float* fm = (const float*)d_in[1];
  const float* pw1 = (const float*)d_in[2];
  const float* pb1 = (const float*)d_in[3];
  const float* g1 = (const float*)d_in[4];
  const float* bb1 = (const float*)d_in[5];
  const float* m1 = (const float*)d_in[6];
  const float* v1 = (const float*)d_in[7];
  const float* pw2 = (const float*)d_in[8];
  const float* pb2 = (const float*)d_in[9];
  const float* aw1 = (const float*)d_in[10];
  const float* ab1 = (const float*)d_in[11];
  const float* g2 = (const float*)d_in[12];
  const float* bb2 = (const float*)d_in[13];
  const float* m2 = (const float*)d_in[14];
  const float* v2 = (const float*)d_in[15];
  const float* aw2 = (const float*)d_in[16];
  const float* ab2 = (const float*)d_in[17];
  float* out = (float*)d_out;

  char* ws = (char*)d_ws;
  float* fm_t = (float*)ws;                               // 33,554,432 B
  float* G2 = (float*)(ws + 33554432);                    //  8,388,608 B
  int* fpsi = (int*)(ws + 41943040);                      //     32,768 B
  int* knni = (int*)(ws + 41975808);                      //    524,288 B
  float* w1f = (float*)(ws + 42500096);
  float* b1f = w1f + 256;
  float* ab1f = b1f + 64;
  float* pw2t = ab1f + 64;                                // 16384
  float* aw1t = pw2t + 64 * 256;                          // 16384
  float* aw2t = aw1t + 256 * 64;                          // 16640
  float* W12t = aw2t + 64 * 260;                          // 4096

  hipLaunchKernelGGL(transpose_fm, dim3(64, 4, 8), dim3(64, 4), 0, stream, fm, fm_t);
  hipLaunchKernelGGL(prep_small, dim3(1), dim3(256), 0, stream,
                     pw1, pb1, g1, bb1, m1, v1, pw2, aw1, ab1, g2, bb2, m2, v2,
                     aw2, w1f, b1f, ab1f, pw2t, aw1t, aw2t);
  hipLaunchKernelGGL(w12_kernel, dim3(16), dim3(256), 0, stream,
                     pw2, aw1, g2, v2, W12t);
  hipLaunchKernelGGL(fps_kernel, dim3(8), dim3(512), 0, stream, verts, fpsi);
  hipLaunchKernelGGL(knn_kernel, dim3(8192), dim3(64), 0, stream, verts, fpsi, knni);
  hipLaunchKernelGGL(g2_kernel, dim3(64, 8), dim3(256), 0, stream, fm, aw1t, G2);
  hipLaunchKernelGGL(fuse_kernel, dim3(8192), dim3(256), 0, stream,
                     verts, fm_t, G2, fpsi, knni, w1f, b1f, ab1f, aw1t, W12t,
                     pw2t, pb2, aw2t, ab2, out);
}

// Round 5
// 1392.771 us; speedup vs baseline: 4.8076x; 1.0449x over previous
//
#include <hip/hip_runtime.h>
#include <math.h>

#define BB 8
#define NN 4096
#define CC 256
#define DD 64
#define MM 1024
#define KNB 16
#define OC 259

// ---------------------------------------------------------------------------
// Transpose feature_map (B,C,N) -> (B,N,C) for coalesced per-point gathers.
__global__ __launch_bounds__(256) void transpose_fm(const float* __restrict__ fm,
                                                    float* __restrict__ fm_t) {
  __shared__ float tile[64][65];
  int b = blockIdx.z;
  int n0 = blockIdx.x * 64;
  int c0 = blockIdx.y * 64;
  const float* src = fm + (size_t)b * CC * NN;
  float* dst = fm_t + (size_t)b * NN * CC;
  int tx = threadIdx.x, ty = threadIdx.y;
  for (int r = ty; r < 64; r += 4)
    tile[r][tx] = src[(size_t)(c0 + r) * NN + n0 + tx];
  __syncthreads();
  for (int r = ty; r < 64; r += 4)
    dst[(size_t)(n0 + r) * CC + c0 + tx] = tile[tx][r];
}

// ---------------------------------------------------------------------------
// Small weight prep: BN folds + transposes.
__global__ void prep_small(
    const float* __restrict__ pw1, const float* __restrict__ pb1,
    const float* __restrict__ g1, const float* __restrict__ bb1,
    const float* __restrict__ m1, const float* __restrict__ v1,
    const float* __restrict__ pw2,
    const float* __restrict__ aw1, const float* __restrict__ ab1,
    const float* __restrict__ g2, const float* __restrict__ bb2,
    const float* __restrict__ m2, const float* __restrict__ v2,
    const float* __restrict__ aw2,
    float* __restrict__ w1f, float* __restrict__ b1f, float* __restrict__ ab1f,
    float* __restrict__ pw2t, float* __restrict__ aw1t, float* __restrict__ aw2t) {
  int tid = threadIdx.x;
  if (tid < 64) {
    float s = g1[tid] * rsqrtf(v1[tid] + 1e-5f);
    w1f[tid * 4 + 0] = pw1[tid * 3 + 0] * s;
    w1f[tid * 4 + 1] = pw1[tid * 3 + 1] * s;
    w1f[tid * 4 + 2] = pw1[tid * 3 + 2] * s;
    w1f[tid * 4 + 3] = 0.f;
    b1f[tid] = (pb1[tid] - m1[tid]) * s + bb1[tid];
    float s2 = g2[tid] * rsqrtf(v2[tid] + 1e-5f);
    ab1f[tid] = (ab1[tid] - m2[tid]) * s2 + bb2[tid];
  }
  for (int x = tid; x < 64 * 256; x += 256) {   // pw2t[i][c] = pw2[c][i]
    int i = x >> 8, c = x & 255;
    pw2t[x] = pw2[c * 64 + i];
  }
  for (int x = tid; x < 256 * 64; x += 256) {   // aw1t[c][d] = aw1[d][c]*s2[d]
    int c = x >> 6, d = x & 63;
    float s2 = g2[d] * rsqrtf(v2[d] + 1e-5f);
    aw1t[x] = aw1[d * 256 + c] * s2;
  }
  for (int x = tid; x < 64 * OC; x += 256) {    // aw2t[i][o] = aw2[o][i]
    int i = x / OC, o = x % OC;
    aw2t[i * 260 + o] = aw2[o * 64 + i];
  }
}

// W12t[i][d] = sum_c pw2[c][i]*aw1[d][c]*s2[d]
__global__ __launch_bounds__(256) void w12_kernel(
    const float* __restrict__ pw2, const float* __restrict__ aw1,
    const float* __restrict__ g2, const float* __restrict__ v2,
    float* __restrict__ W12t) {
  int i = threadIdx.x & 63;
  int d = blockIdx.x * 4 + (threadIdx.x >> 6);
  float s2 = g2[d] * rsqrtf(v2[d] + 1e-5f);
  const float* arow = aw1 + d * 256;
  float s = 0.f;
#pragma unroll 4
  for (int c = 0; c < 256; ++c) s += pw2[c * 64 + i] * arow[c];
  W12t[i * 64 + d] = s * s2;
}

// ---------------------------------------------------------------------------
// FPS v4: v2's reference-exact distance update ((p-c)^2 form — matches the
// jnp.sum((xyz-centroid)**2) reference; do NOT use the expanded form, it
// flips argmax near-ties) + v3's slim two-pass reduction:
//   pass 1: value-only DPP f32-max chain -> readlane(63)
//   pass 2: min-index among dist==max via DPP u32-min chain
// Per-wave packed u64 slots (parity-buffered), depth-3 tree combine.
__global__ __launch_bounds__(512, 2) void fps_kernel(const float* __restrict__ verts,
                                                     int* __restrict__ fps_idx) {
  int b = blockIdx.x;
  int tid = threadIdx.x;
  __shared__ float lx[NN], ly[NN], lz[NN];
  __shared__ __attribute__((aligned(16))) unsigned long long wres[2][8];
  const float* vb = verts + (size_t)b * 3 * NN;
  float px[8], py[8], pz[8], dist[8];
#pragma unroll
  for (int r = 0; r < 8; ++r) {
    int j = tid + r * 512;
    px[r] = vb[j];
    py[r] = vb[NN + j];
    pz[r] = vb[2 * NN + j];
    lx[j] = px[r]; ly[j] = py[r]; lz[j] = pz[r];
    dist[r] = 1e10f;
  }
  __syncthreads();
  int far = 0;
  for (int s = 0; s < MM; ++s) {
    if (tid == 0) fps_idx[b * MM + s] = far;
    if (s == MM - 1) break;
    float cx = lx[far], cy = ly[far], cz = lz[far];
    // pass 1: dist update (reference-exact form) + value max
    float vmax = -1.0f;
#pragma unroll
    for (int r = 0; r < 8; ++r) {
      float dx = px[r] - cx, dy = py[r] - cy, dz = pz[r] - cz;
      float d = dx * dx + dy * dy + dz * dz;
      dist[r] = fminf(dist[r], d);
      vmax = fmaxf(vmax, dist[r]);
    }
#define VRED(CTRL)                                                              \
    {                                                                           \
      int o = __builtin_amdgcn_update_dpp(__float_as_int(vmax),                 \
                                          __float_as_int(vmax), CTRL, 0xF, 0xF, \
                                          false);                               \
      vmax = fmaxf(vmax, __int_as_float(o));                                    \
    }
    VRED(0x111) VRED(0x112) VRED(0x114) VRED(0x118) VRED(0x142) VRED(0x143)
#undef VRED
    float svmax = __int_as_float(__builtin_amdgcn_readlane(__float_as_int(vmax), 63));
    // pass 2: min index among dist == wave max
    int minj = 0x7FFFFFFF;
#pragma unroll
    for (int r = 0; r < 8; ++r) {
      int cand = (dist[r] == svmax) ? (tid + r * 512) : 0x7FFFFFFF;
      minj = (cand < minj) ? cand : minj;
    }
#define IRED(CTRL)                                                             \
    {                                                                          \
      int o = __builtin_amdgcn_update_dpp(minj, minj, CTRL, 0xF, 0xF, false);  \
      minj = (o < minj) ? o : minj;                                            \
    }
    IRED(0x111) IRED(0x112) IRED(0x114) IRED(0x118) IRED(0x142) IRED(0x143)
#undef IRED
    if ((tid & 63) == 63)
      wres[s & 1][tid >> 6] =
          ((unsigned long long)(unsigned)__float_as_int(svmax) << 12) |
          (unsigned long long)(4095 - minj);
    __syncthreads();
    unsigned long long k0 = wres[s & 1][0], k1 = wres[s & 1][1];
    unsigned long long k2 = wres[s & 1][2], k3 = wres[s & 1][3];
    unsigned long long k4 = wres[s & 1][4], k5 = wres[s & 1][5];
    unsigned long long k6 = wres[s & 1][6], k7 = wres[s & 1][7];
    unsigned long long a = (k0 > k1) ? k0 : k1;
    unsigned long long c = (k2 > k3) ? k2 : k3;
    unsigned long long e = (k4 > k5) ? k4 : k5;
    unsigned long long g = (k6 > k7) ? k6 : k7;
    a = (c > a) ? c : a;
    e = (g > e) ? g : e;
    a = (e > a) ? e : a;
    far = 4095 - (int)(a & 0xFFFull);
  }
}

// ---------------------------------------------------------------------------
// KNN top-16: one wave per key point (verified; expanded distance form here
// MATCHES the reference's sqr expression).
__global__ __launch_bounds__(64) void knn_kernel(const float* __restrict__ verts,
                                                 const int* __restrict__ fps_idx,
                                                 int* __restrict__ knn_idx) {
  int blk = blockIdx.x;
  int b = blk >> 10;
  int m = blk & 1023;
  int lane = threadIdx.x;
  __shared__ float dbuf[64 * 65];
  const float* vb = verts + (size_t)b * 3 * NN;
  int jm = fps_idx[b * MM + m];
  float kx = vb[jm], ky = vb[NN + jm], kz = vb[2 * NN + jm];
  float kn = kx * kx + ky * ky + kz * kz;
  float v1 = INFINITY, v2 = INFINITY;
  int i1 = -1, i2 = -1;
  for (int t = 0; t < 64; ++t) {
    int j = t * 64 + lane;
    float x = vb[j], y = vb[NN + j], z = vb[2 * NN + j];
    float xn = x * x + y * y + z * z;
    float d = kn + xn - 2.0f * (kx * x + ky * y + kz * z);
    dbuf[lane * 65 + t] = d;
    if (d < v1) { v2 = v1; i2 = i1; v1 = d; i1 = j; }
    else if (d < v2) { v2 = d; i2 = j; }
  }
  for (int it = 0; it < KNB; ++it) {
    float rv = v1;
    int ri = i1;
#pragma unroll
    for (int off = 32; off >= 1; off >>= 1) {
      float ov = __shfl_down(rv, off, 64);
      int oi = __shfl_down(ri, off, 64);
      if (ov < rv || (ov == rv && oi < ri)) { rv = ov; ri = oi; }
    }
    ri = __shfl(ri, 0, 64);
    if (lane == 0) knn_idx[(size_t)(b * MM + m) * KNB + it] = ri;
    if (i1 == ri) {
      dbuf[lane * 65 + (ri >> 6)] = INFINITY;
      v1 = v2; i1 = i2;
      v2 = INFINITY; i2 = -1;
      if (i1 < 0) {
        v1 = INFINITY; v2 = INFINITY; i1 = -1; i2 = -1;
        for (int t = 0; t < 64; ++t) {
          float d = dbuf[lane * 65 + t];
          int j = t * 64 + lane;
          if (d < v1) { v2 = v1; i2 = i1; v1 = d; i1 = j; }
          else if (d < v2) { v2 = d; i2 = j; }
        }
      }
    }
  }
}

// ---------------------------------------------------------------------------
// G2[b][n][d] = sum_c aw1t[c][d] * fm[b][c][n]  — tiled fp32 GEMM.
__global__ __launch_bounds__(256) void g2_kernel(const float* __restrict__ fm,
                                                 const float* __restrict__ aw1t,
                                                 float* __restrict__ G2) {
  __shared__ __attribute__((aligned(16))) float a_l[64][68];
  __shared__ __attribute__((aligned(16))) float b_l[64][68];
  int b = blockIdx.y;
  int n0 = blockIdx.x * 64;
  int tid = threadIdx.x;
  int rr = tid >> 4, q4 = tid & 15;
  float acc[4][4];
#pragma unroll
  for (int q = 0; q < 4; ++q)
#pragma unroll
    for (int x = 0; x < 4; ++x) acc[q][x] = 0.f;
  for (int c0 = 0; c0 < 256; c0 += 64) {
    __syncthreads();
#pragma unroll
    for (int rep = 0; rep < 4; ++rep) {
      int cc = rr + rep * 16;
      *(float4*)&a_l[cc][q4 * 4] =
          *(const float4*)&fm[((size_t)b * CC + c0 + cc) * NN + n0 + q4 * 4];
      *(float4*)&b_l[cc][q4 * 4] = *(const float4*)&aw1t[(c0 + cc) * 64 + q4 * 4];
    }
    __syncthreads();
#pragma unroll 8
    for (int kk = 0; kk < 64; ++kk) {
      float4 a4 = *(const float4*)&a_l[kk][rr * 4];
      float4 b4 = *(const float4*)&b_l[kk][q4 * 4];
      float av[4] = {a4.x, a4.y, a4.z, a4.w};
#pragma unroll
      for (int q = 0; q < 4; ++q) {
        acc[q][0] += av[q] * b4.x;
        acc[q][1] += av[q] * b4.y;
        acc[q][2] += av[q] * b4.z;
        acc[q][3] += av[q] * b4.w;
      }
    }
  }
#pragma unroll
  for (int q = 0; q < 4; ++q)
    *(float4*)&G2[((size_t)b * NN + n0 + rr * 4 + q) * 64 + q4 * 4] =
        make_float4(acc[q][0], acc[q][1], acc[q][2], acc[q][3]);
}

// ---------------------------------------------------------------------------
// Fused per-(b,m). Register-frugal stage D (max 16-float arrays).
__global__ __launch_bounds__(256, 3) void fuse_kernel(
    const float* __restrict__ verts, const float* __restrict__ fm_t,
    const float* __restrict__ G2,
    const int* __restrict__ fpsi, const int* __restrict__ knni,
    const float* __restrict__ w1f, const float* __restrict__ b1f,
    const float* __restrict__ ab1f, const float* __restrict__ aw1t,
    const float* __restrict__ W12t, const float* __restrict__ pw2t,
    const float* __restrict__ pb2, const float* __restrict__ aw2t,
    const float* __restrict__ ab2, float* __restrict__ out) {
  int bm = blockIdx.x;
  int b = bm & 7, m = bm >> 3;  // batch -> XCD pinning
  int tid = threadIdx.x;

  __shared__ __attribute__((aligned(16))) float kfpb[256];
  __shared__ __attribute__((aligned(16))) float pb2_l[256];
  __shared__ __attribute__((aligned(16))) float gp[3][16];
  __shared__ __attribute__((aligned(16))) float kp[4];
  __shared__ int kidx[16];
  __shared__ __attribute__((aligned(16))) float W12_l[64][68];
  __shared__ __attribute__((aligned(16))) float h_l[16][68];
  __shared__ __attribute__((aligned(16))) float hT_l[64][20];
  __shared__ __attribute__((aligned(16))) float h2T_l[64][20];
  __shared__ __attribute__((aligned(16))) float vmp[4][64];
  __shared__ __attribute__((aligned(16))) float vm_l[64];

  const float* vb = verts + (size_t)b * 3 * NN;
  const float* fb = fm_t + (size_t)b * NN * CC;
  int jm = fpsi[b * MM + m];
  if (tid < 16) kidx[tid] = knni[((size_t)b * MM + m) * 16 + tid];
  kfpb[tid] = fb[(size_t)jm * CC + tid] + pb2[tid];
  pb2_l[tid] = pb2[tid];
  if (tid < 3) kp[tid] = vb[tid * NN + jm];
  __syncthreads();

  if (tid < 48) {
    int c = tid >> 4, k = tid & 15;
    gp[c][k] = vb[c * NN + kidx[k]];
  }
  {
    int i = tid >> 4, d4 = tid & 15;
#pragma unroll
    for (int rep = 0; rep < 4; ++rep)
      *(float4*)&W12_l[i + rep * 16][d4 * 4] =
          *(const float4*)&W12t[(i + rep * 16) * 64 + d4 * 4];
  }
  {
    int d = tid & 63, part = tid >> 6;
    float acc = 0.f;
#pragma unroll 4
    for (int cc = 0; cc < 64; ++cc) {
      int c = part * 64 + cc;
      acc += aw1t[c * 64 + d] * kfpb[c];
    }
    vmp[part][d] = acc;
  }
  __syncthreads();
  if (tid < 64)
    vm_l[tid] = vmp[0][tid] + vmp[1][tid] + vmp[2][tid] + vmp[3][tid] + ab1f[tid];

  {
    int d = tid & 63, part = tid >> 6;
    float wd0 = w1f[d * 4 + 0], wd1 = w1f[d * 4 + 1], wd2 = w1f[d * 4 + 2];
    float bd = b1f[d];
#pragma unroll
    for (int j = 0; j < 4; ++j) {
      int k = part * 4 + j;
      float hv = wd0 * (kp[0] - gp[0][k]) + wd1 * (kp[1] - gp[1][k]) +
                 wd2 * (kp[2] - gp[2][k]) + bd;
      hv = (hv > 0.f) ? hv : 0.2f * hv;
      h_l[k][d] = hv;
      hT_l[d][k] = hv;
    }
  }
  __syncthreads();

  {
    int k = tid & 15, d2 = tid >> 4;
    float4 g4 = *(const float4*)&G2[((size_t)b * NN + kidx[k]) * 64 + d2 * 4];
    float a0 = 0.f, a1 = 0.f, a2 = 0.f, a3 = 0.f;
#pragma unroll 4
    for (int i = 0; i < 64; ++i) {
      float hv = h_l[k][i];
      float4 w4 = *(const float4*)&W12_l[i][d2 * 4];
      a0 += hv * w4.x; a1 += hv * w4.y; a2 += hv * w4.z; a3 += hv * w4.w;
    }
    float4 v4 = *(const float4*)&vm_l[d2 * 4];
    float r0 = v4.x - g4.x + a0;
    float r1 = v4.y - g4.y + a1;
    float r2 = v4.z - g4.z + a2;
    float r3 = v4.w - g4.w + a3;
    h2T_l[d2 * 4 + 0][k] = (r0 > 0.f) ? r0 : 0.2f * r0;
    h2T_l[d2 * 4 + 1][k] = (r1 > 0.f) ? r1 : 0.2f * r1;
    h2T_l[d2 * 4 + 2][k] = (r2 > 0.f) ? r2 : 0.2f * r2;
    h2T_l[d2 * 4 + 3][k] = (r3 > 0.f) ? r3 : 0.2f * r3;
  }
  __syncthreads();

  if (tid < 3) {
    float lg[16];
    float bias = ab2[tid];
#pragma unroll
    for (int k = 0; k < 16; ++k) lg[k] = bias;
    const float* wp = aw2t + tid;
    for (int i = 0; i < 64; ++i) {
      float wv = wp[i * 260];
      float4 ha = *(const float4*)&h2T_l[i][0];
      float4 hb = *(const float4*)&h2T_l[i][4];
      float4 hc = *(const float4*)&h2T_l[i][8];
      float4 hd = *(const float4*)&h2T_l[i][12];
      lg[0] += wv * ha.x;  lg[1] += wv * ha.y;  lg[2] += wv * ha.z;  lg[3] += wv * ha.w;
      lg[4] += wv * hb.x;  lg[5] += wv * hb.y;  lg[6] += wv * hb.z;  lg[7] += wv * hb.w;
      lg[8] += wv * hc.x;  lg[9] += wv * hc.y;  lg[10] += wv * hc.z; lg[11] += wv * hc.w;
      lg[12] += wv * hd.x; lg[13] += wv * hd.y; lg[14] += wv * hd.z; lg[15] += wv * hd.w;
    }
    float mx = lg[0];
#pragma unroll
    for (int k = 1; k < 16; ++k) mx = fmaxf(mx, lg[k]);
    float sum = 0.f;
#pragma unroll
    for (int k = 0; k < 16; ++k) { lg[k] = __expf(lg[k] - mx); sum += lg[k]; }
    float inv = 1.f / sum;
    float a2 = 0.f;
#pragma unroll
    for (int k = 0; k < 16; ++k) a2 += lg[k] * gp[tid][k];
    out[((size_t)b * OC + tid) * MM + m] = a2 * inv;
  }

  {
    int o = tid + 3;
    float gfv[16];
#pragma unroll
    for (int k = 0; k < 16; ++k)
      gfv[k] = fb[(size_t)kidx[k] * CC + tid];
    float lg[16];
    float bias = ab2[o];
#pragma unroll
    for (int k = 0; k < 16; ++k) lg[k] = bias;
    const float* wp = aw2t + o;
#pragma unroll 4
    for (int i = 0; i < 64; ++i) {
      float wv = wp[i * 260];
      float4 ha = *(const float4*)&h2T_l[i][0];
      float4 hb = *(const float4*)&h2T_l[i][4];
      float4 hc = *(const float4*)&h2T_l[i][8];
      float4 hd = *(const float4*)&h2T_l[i][12];
      lg[0] += wv * ha.x;  lg[1] += wv * ha.y;  lg[2] += wv * ha.z;  lg[3] += wv * ha.w;
      lg[4] += wv * hb.x;  lg[5] += wv * hb.y;  lg[6] += wv * hb.z;  lg[7] += wv * hb.w;
      lg[8] += wv * hc.x;  lg[9] += wv * hc.y;  lg[10] += wv * hc.z; lg[11] += wv * hc.w;
      lg[12] += wv * hd.x; lg[13] += wv * hd.y; lg[14] += wv * hd.z; lg[15] += wv * hd.w;
    }
    float mx = lg[0];
#pragma unroll
    for (int k = 1; k < 16; ++k) mx = fmaxf(mx, lg[k]);
    float sum = 0.f;
#pragma unroll
    for (int k = 0; k < 16; ++k) { lg[k] = __expf(lg[k] - mx); sum += lg[k]; }
    float inv = 1.f / sum;
#pragma unroll
    for (int k = 0; k < 16; ++k) lg[k] *= inv;
    float acc = 0.f;
#pragma unroll
    for (int k = 0; k < 16; ++k) acc += lg[k] * gfv[k];
    const float* pcol = pw2t + tid;
#pragma unroll 4
    for (int i = 0; i < 64; ++i) {
      float p = pcol[i * 256];
      float4 ha = *(const float4*)&hT_l[i][0];
      float4 hb = *(const float4*)&hT_l[i][4];
      float4 hc = *(const float4*)&hT_l[i][8];
      float4 hd = *(const float4*)&hT_l[i][12];
      float hw = lg[0] * ha.x + lg[1] * ha.y + lg[2] * ha.z + lg[3] * ha.w +
                 lg[4] * hb.x + lg[5] * hb.y + lg[6] * hb.z + lg[7] * hb.w +
                 lg[8] * hc.x + lg[9] * hc.y + lg[10] * hc.z + lg[11] * hc.w +
                 lg[12] * hd.x + lg[13] * hd.y + lg[14] * hd.z + lg[15] * hd.w;
      acc += p * hw;
    }
    out[((size_t)b * OC + o) * MM + m] = pb2_l[tid] + acc;
  }
}

// ---------------------------------------------------------------------------
extern "C" void kernel_launch(void* const* d_in, const int* in_sizes, int n_in,
                              void* d_out, int out_size, void* d_ws, size_t ws_size,
                              hipStream_t stream) {
  (void)in_sizes; (void)n_in; (void)out_size; (void)ws_size;
  const float* verts = (const float*)d_in[0];
  const float* fm = (const float*)d_in[1];
  const float* pw1 = (const float*)d_in[2];
  const float* pb1 = (const float*)d_in[3];
  const float* g1 = (const float*)d_in[4];
  const float* bb1 = (const float*)d_in[5];
  const float* m1 = (const float*)d_in[6];
  const float* v1 = (const float*)d_in[7];
  const float* pw2 = (const float*)d_in[8];
  const float* pb2 = (const float*)d_in[9];
  const float* aw1 = (const float*)d_in[10];
  const float* ab1 = (const float*)d_in[11];
  const float* g2 = (const float*)d_in[12];
  const float* bb2 = (const float*)d_in[13];
  const float* m2 = (const float*)d_in[14];
  const float* v2 = (const float*)d_in[15];
  const float* aw2 = (const float*)d_in[16];
  const float* ab2 = (const float*)d_in[17];
  float* out = (float*)d_out;

  char* ws = (char*)d_ws;
  float* fm_t = (float*)ws;                               // 33,554,432 B
  float* G2 = (float*)(ws + 33554432);                    //  8,388,608 B
  int* fpsi = (int*)(ws + 41943040);                      //     32,768 B
  int* knni = (int*)(ws + 41975808);                      //    524,288 B
  float* w1f = (float*)(ws + 42500096);
  float* b1f = w1f + 256;
  float* ab1f = b1f + 64;
  float* pw2t = ab1f + 64;
  float* aw1t = pw2t + 64 * 256;
  float* aw2t = aw1t + 256 * 64;
  float* W12t = aw2t + 64 * 260;

  hipLaunchKernelGGL(transpose_fm, dim3(64, 4, 8), dim3(64, 4), 0, stream, fm, fm_t);
  hipLaunchKernelGGL(prep_small, dim3(1), dim3(256), 0, stream,
                     pw1, pb1, g1, bb1, m1, v1, pw2, aw1, ab1, g2, bb2, m2, v2,
                     aw2, w1f, b1f, ab1f, pw2t, aw1t, aw2t);
  hipLaunchKernelGGL(w12_kernel, dim3(16), dim3(256), 0, stream,
                     pw2, aw1, g2, v2, W12t);
  hipLaunchKernelGGL(fps_kernel, dim3(8), dim3(512), 0, stream, verts, fpsi);
  hipLaunchKernelGGL(knn_kernel, dim3(8192), dim3(64), 0, stream, verts, fpsi, knni);
  hipLaunchKernelGGL(g2_kernel, dim3(64, 8), dim3(256), 0, stream, fm, aw1t, G2);
  hipLaunchKernelGGL(fuse_kernel, dim3(8192), dim3(256), 0, stream,
                     verts, fm_t, G2, fpsi, knni, w1f, b1f, ab1f, aw1t, W12t,
                     pw2t, pb2, aw2t, ab2, out);
}

// Round 6
// 1222.535 us; speedup vs baseline: 5.4770x; 1.1392x over previous
//
#include <hip/hip_runtime.h>
#include <math.h>

#define BB 8
#define NN 4096
#define CC 256
#define DD 64
#define MM 1024
#define KNB 16
#define OC 259

// ---------------------------------------------------------------------------
// Transpose feature_map (B,C,N) -> (B,N,C) for coalesced per-point gathers.
__global__ __launch_bounds__(256) void transpose_fm(const float* __restrict__ fm,
                                                    float* __restrict__ fm_t) {
  __shared__ float tile[64][65];
  int b = blockIdx.z;
  int n0 = blockIdx.x * 64;
  int c0 = blockIdx.y * 64;
  const float* src = fm + (size_t)b * CC * NN;
  float* dst = fm_t + (size_t)b * NN * CC;
  int tx = threadIdx.x, ty = threadIdx.y;
  for (int r = ty; r < 64; r += 4)
    tile[r][tx] = src[(size_t)(c0 + r) * NN + n0 + tx];
  __syncthreads();
  for (int r = ty; r < 64; r += 4)
    dst[(size_t)(n0 + r) * CC + c0 + tx] = tile[tx][r];
}

// ---------------------------------------------------------------------------
// Small weight prep: BN folds + transposes.
__global__ void prep_small(
    const float* __restrict__ pw1, const float* __restrict__ pb1,
    const float* __restrict__ g1, const float* __restrict__ bb1,
    const float* __restrict__ m1, const float* __restrict__ v1,
    const float* __restrict__ pw2,
    const float* __restrict__ aw1, const float* __restrict__ ab1,
    const float* __restrict__ g2, const float* __restrict__ bb2,
    const float* __restrict__ m2, const float* __restrict__ v2,
    const float* __restrict__ aw2,
    float* __restrict__ w1f, float* __restrict__ b1f, float* __restrict__ ab1f,
    float* __restrict__ pw2t, float* __restrict__ aw1t, float* __restrict__ aw2t) {
  int tid = threadIdx.x;
  if (tid < 64) {
    float s = g1[tid] * rsqrtf(v1[tid] + 1e-5f);
    w1f[tid * 4 + 0] = pw1[tid * 3 + 0] * s;
    w1f[tid * 4 + 1] = pw1[tid * 3 + 1] * s;
    w1f[tid * 4 + 2] = pw1[tid * 3 + 2] * s;
    w1f[tid * 4 + 3] = 0.f;
    b1f[tid] = (pb1[tid] - m1[tid]) * s + bb1[tid];
    float s2 = g2[tid] * rsqrtf(v2[tid] + 1e-5f);
    ab1f[tid] = (ab1[tid] - m2[tid]) * s2 + bb2[tid];
  }
  for (int x = tid; x < 64 * 256; x += 256) {   // pw2t[i][c] = pw2[c][i]
    int i = x >> 8, c = x & 255;
    pw2t[x] = pw2[c * 64 + i];
  }
  for (int x = tid; x < 256 * 64; x += 256) {   // aw1t[c][d] = aw1[d][c]*s2[d]
    int c = x >> 6, d = x & 63;
    float s2 = g2[d] * rsqrtf(v2[d] + 1e-5f);
    aw1t[x] = aw1[d * 256 + c] * s2;
  }
  for (int x = tid; x < 64 * OC; x += 256) {    // aw2t[i][o] = aw2[o][i]
    int i = x / OC, o = x % OC;
    aw2t[i * 260 + o] = aw2[o * 64 + i];
  }
}

// W12t[i][d] = sum_c pw2[c][i]*aw1[d][c]*s2[d]
__global__ __launch_bounds__(256) void w12_kernel(
    const float* __restrict__ pw2, const float* __restrict__ aw1,
    const float* __restrict__ g2, const float* __restrict__ v2,
    float* __restrict__ W12t) {
  int i = threadIdx.x & 63;
  int d = blockIdx.x * 4 + (threadIdx.x >> 6);
  float s2 = g2[d] * rsqrtf(v2[d] + 1e-5f);
  const float* arow = aw1 + d * 256;
  float s = 0.f;
#pragma unroll 4
  for (int c = 0; c < 256; ++c) s += pw2[c * 64 + i] * arow[c];
  W12t[i * 64 + d] = s * s2;
}

// ---------------------------------------------------------------------------
// FPS v5: 256 threads (1 wave/SIMD), 16 pts/thread.
// - NO global stores in the step loop: selected indices buffered in LDS
//   (fps_l) and bulk-stored after the loop. The compiler's mandatory
//   `s_waitcnt vmcnt(0)` before each s_barrier was draining wave-0's
//   per-step HBM store — that was the hidden serial cost.
// - Distance update byte-identical to the reference-exact (p-c)^2 form.
// - Two-pass wave reduce (DPP f32-max chain -> readlane; DPP u32-min index),
//   4 packed u64 slots (parity-buffered), depth-2 tree combine.
__global__ __launch_bounds__(256, 2) void fps_kernel(const float* __restrict__ verts,
                                                     int* __restrict__ fps_idx) {
  int b = blockIdx.x;
  int tid = threadIdx.x;
  __shared__ float lx[NN], ly[NN], lz[NN];
  __shared__ __attribute__((aligned(16))) unsigned long long wres[2][4];
  __shared__ int fps_l[MM];
  const float* vb = verts + (size_t)b * 3 * NN;
  float px[16], py[16], pz[16], dist[16];
#pragma unroll
  for (int r = 0; r < 16; ++r) {
    int j = tid + r * 256;
    px[r] = vb[j];
    py[r] = vb[NN + j];
    pz[r] = vb[2 * NN + j];
    lx[j] = px[r]; ly[j] = py[r]; lz[j] = pz[r];
    dist[r] = 1e10f;
  }
  __syncthreads();
  int far = 0;
  for (int s = 0; s < MM; ++s) {
    if (tid == 0) fps_l[s] = far;
    if (s == MM - 1) break;
    float cx = lx[far], cy = ly[far], cz = lz[far];
    // pass 1: dist update (reference-exact form) + value max
    float vmax = -1.0f;
#pragma unroll
    for (int r = 0; r < 16; ++r) {
      float dx = px[r] - cx, dy = py[r] - cy, dz = pz[r] - cz;
      float d = dx * dx + dy * dy + dz * dz;
      dist[r] = fminf(dist[r], d);
      vmax = fmaxf(vmax, dist[r]);
    }
#define VRED(CTRL)                                                              \
    {                                                                           \
      int o = __builtin_amdgcn_update_dpp(__float_as_int(vmax),                 \
                                          __float_as_int(vmax), CTRL, 0xF, 0xF, \
                                          false);                               \
      vmax = fmaxf(vmax, __int_as_float(o));                                    \
    }
    VRED(0x111) VRED(0x112) VRED(0x114) VRED(0x118) VRED(0x142) VRED(0x143)
#undef VRED
    float svmax = __int_as_float(__builtin_amdgcn_readlane(__float_as_int(vmax), 63));
    // pass 2: min index among dist == wave max
    int minj = 0x7FFFFFFF;
#pragma unroll
    for (int r = 0; r < 16; ++r) {
      int cand = (dist[r] == svmax) ? (tid + r * 256) : 0x7FFFFFFF;
      minj = (cand < minj) ? cand : minj;
    }
#define IRED(CTRL)                                                             \
    {                                                                          \
      int o = __builtin_amdgcn_update_dpp(minj, minj, CTRL, 0xF, 0xF, false);  \
      minj = (o < minj) ? o : minj;                                            \
    }
    IRED(0x111) IRED(0x112) IRED(0x114) IRED(0x118) IRED(0x142) IRED(0x143)
#undef IRED
    if ((tid & 63) == 63)
      wres[s & 1][tid >> 6] =
          ((unsigned long long)(unsigned)__float_as_int(svmax) << 12) |
          (unsigned long long)(4095 - minj);
    __syncthreads();
    unsigned long long k0 = wres[s & 1][0], k1 = wres[s & 1][1];
    unsigned long long k2 = wres[s & 1][2], k3 = wres[s & 1][3];
    unsigned long long a = (k0 > k1) ? k0 : k1;
    unsigned long long c = (k2 > k3) ? k2 : k3;
    a = (c > a) ? c : a;
    far = 4095 - (int)(a & 0xFFFull);
  }
  __syncthreads();
  // bulk coalesced store of the 1024 selected indices
#pragma unroll
  for (int x = tid; x < MM; x += 256) fps_idx[b * MM + x] = fps_l[x];
}

// ---------------------------------------------------------------------------
// KNN top-16: one wave per key point (verified; expanded distance form here
// MATCHES the reference's sqr expression).
__global__ __launch_bounds__(64) void knn_kernel(const float* __restrict__ verts,
                                                 const int* __restrict__ fps_idx,
                                                 int* __restrict__ knn_idx) {
  int blk = blockIdx.x;
  int b = blk >> 10;
  int m = blk & 1023;
  int lane = threadIdx.x;
  __shared__ float dbuf[64 * 65];
  const float* vb = verts + (size_t)b * 3 * NN;
  int jm = fps_idx[b * MM + m];
  float kx = vb[jm], ky = vb[NN + jm], kz = vb[2 * NN + jm];
  float kn = kx * kx + ky * ky + kz * kz;
  float v1 = INFINITY, v2 = INFINITY;
  int i1 = -1, i2 = -1;
  for (int t = 0; t < 64; ++t) {
    int j = t * 64 + lane;
    float x = vb[j], y = vb[NN + j], z = vb[2 * NN + j];
    float xn = x * x + y * y + z * z;
    float d = kn + xn - 2.0f * (kx * x + ky * y + kz * z);
    dbuf[lane * 65 + t] = d;
    if (d < v1) { v2 = v1; i2 = i1; v1 = d; i1 = j; }
    else if (d < v2) { v2 = d; i2 = j; }
  }
  for (int it = 0; it < KNB; ++it) {
    float rv = v1;
    int ri = i1;
#pragma unroll
    for (int off = 32; off >= 1; off >>= 1) {
      float ov = __shfl_down(rv, off, 64);
      int oi = __shfl_down(ri, off, 64);
      if (ov < rv || (ov == rv && oi < ri)) { rv = ov; ri = oi; }
    }
    ri = __shfl(ri, 0, 64);
    if (lane == 0) knn_idx[(size_t)(b * MM + m) * KNB + it] = ri;
    if (i1 == ri) {
      dbuf[lane * 65 + (ri >> 6)] = INFINITY;
      v1 = v2; i1 = i2;
      v2 = INFINITY; i2 = -1;
      if (i1 < 0) {
        v1 = INFINITY; v2 = INFINITY; i1 = -1; i2 = -1;
        for (int t = 0; t < 64; ++t) {
          float d = dbuf[lane * 65 + t];
          int j = t * 64 + lane;
          if (d < v1) { v2 = v1; i2 = i1; v1 = d; i1 = j; }
          else if (d < v2) { v2 = d; i2 = j; }
        }
      }
    }
  }
}

// ---------------------------------------------------------------------------
// G2[b][n][d] = sum_c aw1t[c][d] * fm[b][c][n]  — tiled fp32 GEMM.
__global__ __launch_bounds__(256) void g2_kernel(const float* __restrict__ fm,
                                                 const float* __restrict__ aw1t,
                                                 float* __restrict__ G2) {
  __shared__ __attribute__((aligned(16))) float a_l[64][68];
  __shared__ __attribute__((aligned(16))) float b_l[64][68];
  int b = blockIdx.y;
  int n0 = blockIdx.x * 64;
  int tid = threadIdx.x;
  int rr = tid >> 4, q4 = tid & 15;
  float acc[4][4];
#pragma unroll
  for (int q = 0; q < 4; ++q)
#pragma unroll
    for (int x = 0; x < 4; ++x) acc[q][x] = 0.f;
  for (int c0 = 0; c0 < 256; c0 += 64) {
    __syncthreads();
#pragma unroll
    for (int rep = 0; rep < 4; ++rep) {
      int cc = rr + rep * 16;
      *(float4*)&a_l[cc][q4 * 4] =
          *(const float4*)&fm[((size_t)b * CC + c0 + cc) * NN + n0 + q4 * 4];
      *(float4*)&b_l[cc][q4 * 4] = *(const float4*)&aw1t[(c0 + cc) * 64 + q4 * 4];
    }
    __syncthreads();
#pragma unroll 8
    for (int kk = 0; kk < 64; ++kk) {
      float4 a4 = *(const float4*)&a_l[kk][rr * 4];
      float4 b4 = *(const float4*)&b_l[kk][q4 * 4];
      float av[4] = {a4.x, a4.y, a4.z, a4.w};
#pragma unroll
      for (int q = 0; q < 4; ++q) {
        acc[q][0] += av[q] * b4.x;
        acc[q][1] += av[q] * b4.y;
        acc[q][2] += av[q] * b4.z;
        acc[q][3] += av[q] * b4.w;
      }
    }
  }
#pragma unroll
  for (int q = 0; q < 4; ++q)
    *(float4*)&G2[((size_t)b * NN + n0 + rr * 4 + q) * 64 + q4 * 4] =
        make_float4(acc[q][0], acc[q][1], acc[q][2], acc[q][3]);
}

// ---------------------------------------------------------------------------
// Fused per-(b,m). Register-frugal stage D (max 16-float arrays).
__global__ __launch_bounds__(256, 3) void fuse_kernel(
    const float* __restrict__ verts, const float* __restrict__ fm_t,
    const float* __restrict__ G2,
    const int* __restrict__ fpsi, const int* __restrict__ knni,
    const float* __restrict__ w1f, const float* __restrict__ b1f,
    const float* __restrict__ ab1f, const float* __restrict__ aw1t,
    const float* __restrict__ W12t, const float* __restrict__ pw2t,
    const float* __restrict__ pb2, const float* __restrict__ aw2t,
    const float* __restrict__ ab2, float* __restrict__ out) {
  int bm = blockIdx.x;
  int b = bm & 7, m = bm >> 3;  // batch -> XCD pinning
  int tid = threadIdx.x;

  __shared__ __attribute__((aligned(16))) float kfpb[256];
  __shared__ __attribute__((aligned(16))) float pb2_l[256];
  __shared__ __attribute__((aligned(16))) float gp[3][16];
  __shared__ __attribute__((aligned(16))) float kp[4];
  __shared__ int kidx[16];
  __shared__ __attribute__((aligned(16))) float W12_l[64][68];
  __shared__ __attribute__((aligned(16))) float h_l[16][68];
  __shared__ __attribute__((aligned(16))) float hT_l[64][20];
  __shared__ __attribute__((aligned(16))) float h2T_l[64][20];
  __shared__ __attribute__((aligned(16))) float vmp[4][64];
  __shared__ __attribute__((aligned(16))) float vm_l[64];

  const float* vb = verts + (size_t)b * 3 * NN;
  const float* fb = fm_t + (size_t)b * NN * CC;
  int jm = fpsi[b * MM + m];
  if (tid < 16) kidx[tid] = knni[((size_t)b * MM + m) * 16 + tid];
  kfpb[tid] = fb[(size_t)jm * CC + tid] + pb2[tid];
  pb2_l[tid] = pb2[tid];
  if (tid < 3) kp[tid] = vb[tid * NN + jm];
  __syncthreads();

  if (tid < 48) {
    int c = tid >> 4, k = tid & 15;
    gp[c][k] = vb[c * NN + kidx[k]];
  }
  {
    int i = tid >> 4, d4 = tid & 15;
#pragma unroll
    for (int rep = 0; rep < 4; ++rep)
      *(float4*)&W12_l[i + rep * 16][d4 * 4] =
          *(const float4*)&W12t[(i + rep * 16) * 64 + d4 * 4];
  }
  {
    int d = tid & 63, part = tid >> 6;
    float acc = 0.f;
#pragma unroll 4
    for (int cc = 0; cc < 64; ++cc) {
      int c = part * 64 + cc;
      acc += aw1t[c * 64 + d] * kfpb[c];
    }
    vmp[part][d] = acc;
  }
  __syncthreads();
  if (tid < 64)
    vm_l[tid] = vmp[0][tid] + vmp[1][tid] + vmp[2][tid] + vmp[3][tid] + ab1f[tid];

  {
    int d = tid & 63, part = tid >> 6;
    float wd0 = w1f[d * 4 + 0], wd1 = w1f[d * 4 + 1], wd2 = w1f[d * 4 + 2];
    float bd = b1f[d];
#pragma unroll
    for (int j = 0; j < 4; ++j) {
      int k = part * 4 + j;
      float hv = wd0 * (kp[0] - gp[0][k]) + wd1 * (kp[1] - gp[1][k]) +
                 wd2 * (kp[2] - gp[2][k]) + bd;
      hv = (hv > 0.f) ? hv : 0.2f * hv;
      h_l[k][d] = hv;
      hT_l[d][k] = hv;
    }
  }
  __syncthreads();

  {
    int k = tid & 15, d2 = tid >> 4;
    float4 g4 = *(const float4*)&G2[((size_t)b * NN + kidx[k]) * 64 + d2 * 4];
    float a0 = 0.f, a1 = 0.f, a2 = 0.f, a3 = 0.f;
#pragma unroll 4
    for (int i = 0; i < 64; ++i) {
      float hv = h_l[k][i];
      float4 w4 = *(const float4*)&W12_l[i][d2 * 4];
      a0 += hv * w4.x; a1 += hv * w4.y; a2 += hv * w4.z; a3 += hv * w4.w;
    }
    float4 v4 = *(const float4*)&vm_l[d2 * 4];
    float r0 = v4.x - g4.x + a0;
    float r1 = v4.y - g4.y + a1;
    float r2 = v4.z - g4.z + a2;
    float r3 = v4.w - g4.w + a3;
    h2T_l[d2 * 4 + 0][k] = (r0 > 0.f) ? r0 : 0.2f * r0;
    h2T_l[d2 * 4 + 1][k] = (r1 > 0.f) ? r1 : 0.2f * r1;
    h2T_l[d2 * 4 + 2][k] = (r2 > 0.f) ? r2 : 0.2f * r2;
    h2T_l[d2 * 4 + 3][k] = (r3 > 0.f) ? r3 : 0.2f * r3;
  }
  __syncthreads();

  if (tid < 3) {
    float lg[16];
    float bias = ab2[tid];
#pragma unroll
    for (int k = 0; k < 16; ++k) lg[k] = bias;
    const float* wp = aw2t + tid;
    for (int i = 0; i < 64; ++i) {
      float wv = wp[i * 260];
      float4 ha = *(const float4*)&h2T_l[i][0];
      float4 hb = *(const float4*)&h2T_l[i][4];
      float4 hc = *(const float4*)&h2T_l[i][8];
      float4 hd = *(const float4*)&h2T_l[i][12];
      lg[0] += wv * ha.x;  lg[1] += wv * ha.y;  lg[2] += wv * ha.z;  lg[3] += wv * ha.w;
      lg[4] += wv * hb.x;  lg[5] += wv * hb.y;  lg[6] += wv * hb.z;  lg[7] += wv * hb.w;
      lg[8] += wv * hc.x;  lg[9] += wv * hc.y;  lg[10] += wv * hc.z; lg[11] += wv * hc.w;
      lg[12] += wv * hd.x; lg[13] += wv * hd.y; lg[14] += wv * hd.z; lg[15] += wv * hd.w;
    }
    float mx = lg[0];
#pragma unroll
    for (int k = 1; k < 16; ++k) mx = fmaxf(mx, lg[k]);
    float sum = 0.f;
#pragma unroll
    for (int k = 0; k < 16; ++k) { lg[k] = __expf(lg[k] - mx); sum += lg[k]; }
    float inv = 1.f / sum;
    float a2 = 0.f;
#pragma unroll
    for (int k = 0; k < 16; ++k) a2 += lg[k] * gp[tid][k];
    out[((size_t)b * OC + tid) * MM + m] = a2 * inv;
  }

  {
    int o = tid + 3;
    float gfv[16];
#pragma unroll
    for (int k = 0; k < 16; ++k)
      gfv[k] = fb[(size_t)kidx[k] * CC + tid];
    float lg[16];
    float bias = ab2[o];
#pragma unroll
    for (int k = 0; k < 16; ++k) lg[k] = bias;
    const float* wp = aw2t + o;
#pragma unroll 4
    for (int i = 0; i < 64; ++i) {
      float wv = wp[i * 260];
      float4 ha = *(const float4*)&h2T_l[i][0];
      float4 hb = *(const float4*)&h2T_l[i][4];
      float4 hc = *(const float4*)&h2T_l[i][8];
      float4 hd = *(const float4*)&h2T_l[i][12];
      lg[0] += wv * ha.x;  lg[1] += wv * ha.y;  lg[2] += wv * ha.z;  lg[3] += wv * ha.w;
      lg[4] += wv * hb.x;  lg[5] += wv * hb.y;  lg[6] += wv * hb.z;  lg[7] += wv * hb.w;
      lg[8] += wv * hc.x;  lg[9] += wv * hc.y;  lg[10] += wv * hc.z; lg[11] += wv * hc.w;
      lg[12] += wv * hd.x; lg[13] += wv * hd.y; lg[14] += wv * hd.z; lg[15] += wv * hd.w;
    }
    float mx = lg[0];
#pragma unroll
    for (int k = 1; k < 16; ++k) mx = fmaxf(mx, lg[k]);
    float sum = 0.f;
#pragma unroll
    for (int k = 0; k < 16; ++k) { lg[k] = __expf(lg[k] - mx); sum += lg[k]; }
    float inv = 1.f / sum;
#pragma unroll
    for (int k = 0; k < 16; ++k) lg[k] *= inv;
    float acc = 0.f;
#pragma unroll
    for (int k = 0; k < 16; ++k) acc += lg[k] * gfv[k];
    const float* pcol = pw2t + tid;
#pragma unroll 4
    for (int i = 0; i < 64; ++i) {
      float p = pcol[i * 256];
      float4 ha = *(const float4*)&hT_l[i][0];
      float4 hb = *(const float4*)&hT_l[i][4];
      float4 hc = *(const float4*)&hT_l[i][8];
      float4 hd = *(const float4*)&hT_l[i][12];
      float hw = lg[0] * ha.x + lg[1] * ha.y + lg[2] * ha.z + lg[3] * ha.w +
                 lg[4] * hb.x + lg[5] * hb.y + lg[6] * hb.z + lg[7] * hb.w +
                 lg[8] * hc.x + lg[9] * hc.y + lg[10] * hc.z + lg[11] * hc.w +
                 lg[12] * hd.x + lg[13] * hd.y + lg[14] * hd.z + lg[15] * hd.w;
      acc += p * hw;
    }
    out[((size_t)b * OC + o) * MM + m] = pb2_l[tid] + acc;
  }
}

// ---------------------------------------------------------------------------
extern "C" void kernel_launch(void* const* d_in, const int* in_sizes, int n_in,
                              void* d_out, int out_size, void* d_ws, size_t ws_size,
                              hipStream_t stream) {
  (void)in_sizes; (void)n_in; (void)out_size; (void)ws_size;
  const float* verts = (const float*)d_in[0];
  const float* fm = (const float*)d_in[1];
  const float* pw1 = (const float*)d_in[2];
  const float* pb1 = (const float*)d_in[3];
  const float* g1 = (const float*)d_in[4];
  const float* bb1 = (const float*)d_in[5];
  const float* m1 = (const float*)d_in[6];
  const float* v1 = (const float*)d_in[7];
  const float* pw2 = (const float*)d_in[8];
  const float* pb2 = (const float*)d_in[9];
  const float* aw1 = (const float*)d_in[10];
  const float* ab1 = (const float*)d_in[11];
  const float* g2 = (const float*)d_in[12];
  const float* bb2 = (const float*)d_in[13];
  const float* m2 = (const float*)d_in[14];
  const float* v2 = (const float*)d_in[15];
  const float* aw2 = (const float*)d_in[16];
  const float* ab2 = (const float*)d_in[17];
  float* out = (float*)d_out;

  char* ws = (char*)d_ws;
  float* fm_t = (float*)ws;                               // 33,554,432 B
  float* G2 = (float*)(ws + 33554432);                    //  8,388,608 B
  int* fpsi = (int*)(ws + 41943040);                      //     32,768 B
  int* knni = (int*)(ws + 41975808);                      //    524,288 B
  float* w1f = (float*)(ws + 42500096);
  float* b1f = w1f + 256;
  float* ab1f = b1f + 64;
  float* pw2t = ab1f + 64;
  float* aw1t = pw2t + 64 * 256;
  float* aw2t = aw1t + 256 * 64;
  float* W12t = aw2t + 64 * 260;

  hipLaunchKernelGGL(transpose_fm, dim3(64, 4, 8), dim3(64, 4), 0, stream, fm, fm_t);
  hipLaunchKernelGGL(prep_small, dim3(1), dim3(256), 0, stream,
                     pw1, pb1, g1, bb1, m1, v1, pw2, aw1, ab1, g2, bb2, m2, v2,
                     aw2, w1f, b1f, ab1f, pw2t, aw1t, aw2t);
  hipLaunchKernelGGL(w12_kernel, dim3(16), dim3(256), 0, stream,
                     pw2, aw1, g2, v2, W12t);
  hipLaunchKernelGGL(fps_kernel, dim3(8), dim3(256), 0, stream, verts, fpsi);
  hipLaunchKernelGGL(knn_kernel, dim3(8192), dim3(64), 0, stream, verts, fpsi, knni);
  hipLaunchKernelGGL(g2_kernel, dim3(64, 8), dim3(256), 0, stream, fm, aw1t, G2);
  hipLaunchKernelGGL(fuse_kernel, dim3(8192), dim3(256), 0, stream,
                     verts, fm_t, G2, fpsi, knni, w1f, b1f, ab1f, aw1t, W12t,
                     pw2t, pb2, aw2t, ab2, out);
}